// Round 12
// baseline (454.967 us; speedup 1.0000x reference)
//
#include <hip/hip_runtime.h>
#include <hip/hip_bf16.h>

typedef __hip_bfloat16 bf16;

#define NEG_SLOPE 0.2f

__device__ __forceinline__ float b2f(bf16 v) { return __bfloat162float(v); }
__device__ __forceinline__ float lrelu(float x) { return x >= 0.f ? x : NEG_SLOPE * x; }
// packed bf16x2 (as uint) -> two floats
__device__ __forceinline__ float2 bf2x(unsigned pv) {
    float2 r;
    r.x = __uint_as_float(pv << 16);
    r.y = __uint_as_float(pv & 0xffff0000u);
    return r;
}

static inline int cdiv(int a, int b) { return (a + b - 1) / b; }

// ---------------- diagnostic fill (ws too small)
__global__ void fill_sentinel(float* __restrict__ y, int n) {
    int t = blockIdx.x * 256 + threadIdx.x;
    if (t < n) y[t] = 2.0f;
}

// ---------------- fused: csr_count (blocks < CB) || layer-1 node transform (FIN=23)
#define CB 2048
__global__ __launch_bounds__(256) void count_and_t1(
    const int* __restrict__ dst, int* __restrict__ counts, int E,
    const int* __restrict__ ids, const float* __restrict__ feats,
    const float* __restrict__ emb, const float* __restrict__ W1,
    const float* __restrict__ a1s, const float* __restrict__ a1d,
    bf16* __restrict__ h_out, float* __restrict__ as_out, float* __restrict__ ad_out, int N) {
    if (blockIdx.x < CB) {  // edge-count part (grid-stride)
        for (int i = blockIdx.x * 256 + threadIdx.x; i < E; i += CB * 256)
            atomicAdd(&counts[dst[i]], 1);
        return;
    }
    // transform part: 2 nodes per block, HC=128, FIN=23 (build x inline)
    constexpr int FIN = 23, FINP = 27, HC = 128;
    __shared__ float xs[2 * FINP];
    const int node0 = (blockIdx.x - CB) * 2;
    const int tid = threadIdx.x;
    if (tid < 2 * FIN) {
        int ln = tid / FIN, f = tid - ln * FIN;
        int i = node0 + ln;
        float v = 0.f;
        if (i < N) v = (f < 8) ? emb[ids[i] * 8 + f] : feats[i * 15 + (f - 8)];
        xs[ln * FINP + f] = v;
    }
    __syncthreads();
    const int ln = tid >> 7, j = tid & 127;
    const int i = node0 + ln;
    if (i >= N) return;
    float acc = 0.f;
#pragma unroll
    for (int f = 0; f < FIN; ++f) acc += xs[ln * FINP + f] * W1[f * HC + j];
    h_out[(size_t)i * HC + j] = __float2bfloat16(acc);
    float s = acc * a1s[j];
    float d = acc * a1d[j];
#pragma unroll
    for (int off = 16; off > 0; off >>= 1) {
        s += __shfl_down(s, off, 32);
        d += __shfl_down(d, off, 32);
    }
    if ((j & 31) == 0) {
        as_out[i * 4 + j / 32] = s;
        ad_out[i * 4 + j / 32] = d;
    }
}

// ---------------- 3-kernel parallel exclusive scan
__global__ void scan_blocksums(const int* __restrict__ counts, int* __restrict__ bsum, int N) {
    __shared__ int s[256];
    int i = blockIdx.x * 256 + threadIdx.x;
    s[threadIdx.x] = (i < N) ? counts[i] : 0;
    __syncthreads();
    for (int o = 128; o > 0; o >>= 1) {
        if (threadIdx.x < o) s[threadIdx.x] += s[threadIdx.x + o];
        __syncthreads();
    }
    if (threadIdx.x == 0) bsum[blockIdx.x] = s[0];
}
__global__ __launch_bounds__(1024) void scan_bsums(int* __restrict__ bsum, int nb) {
    __shared__ int part[1024];
    int t = threadIdx.x;
    int v = (t < nb) ? bsum[t] : 0;
    part[t] = v;
    __syncthreads();
    for (int o = 1; o < 1024; o <<= 1) {
        int u = (t >= o) ? part[t - o] : 0;
        __syncthreads();
        part[t] += u;
        __syncthreads();
    }
    if (t < nb) bsum[t] = part[t] - v;  // exclusive
}
__global__ void scan_final(const int* __restrict__ counts, const int* __restrict__ bsum,
                           int* __restrict__ off, int* __restrict__ cursor, int N) {
    __shared__ int s[256];
    int t = threadIdx.x;
    int i = blockIdx.x * 256 + t;
    int v = (i < N) ? counts[i] : 0;
    s[t] = v;
    __syncthreads();
    for (int o = 1; o < 256; o <<= 1) {
        int u = (t >= o) ? s[t - o] : 0;
        __syncthreads();
        s[t] += u;
        __syncthreads();
    }
    if (i < N) {
        int excl = s[t] - v + bsum[blockIdx.x];
        off[i] = excl;
        cursor[i] = excl;
        if (i == N - 1) off[N] = excl + v;
    }
}
// scatter fill; ushort payload when src fits 16 bits (halves write amplification)
__global__ void csr_fill_u16(const int* __restrict__ src, const int* __restrict__ dst,
                             int* __restrict__ cursor, ushort* __restrict__ elsrc, int E) {
    int t = blockIdx.x * 256 + threadIdx.x;
    if (t >= E) return;
    int slot = atomicAdd(&cursor[dst[t]], 1);
    elsrc[slot] = (ushort)src[t];
}
__global__ void csr_fill_i32(const int* __restrict__ src, const int* __restrict__ dst,
                             int* __restrict__ cursor, int* __restrict__ elsrc, int E) {
    int t = blockIdx.x * 256 + threadIdx.x;
    if (t >= E) return;
    int slot = atomicAdd(&cursor[dst[t]], 1);
    elsrc[slot] = src[t];
}

// ---------------- fused: gat layer k (per-dst wave, shift-by-self softmax)
// + node transform of layer k+1 for the same dst (x row never leaves the wave).
// FINAL=true: sigmoid -> f32 y, no transform.
template <int H, int C, int HN, int CN, bool FINAL, typename EIDX>
__global__ __launch_bounds__(256) void gat_fused(
    const int* __restrict__ csr_off, const EIDX* __restrict__ elsrc,
    const bf16* __restrict__ hbuf, const float* __restrict__ asb,
    const float* __restrict__ adb, const float* __restrict__ bias,
    const float* __restrict__ Wn, const float* __restrict__ anS,
    const float* __restrict__ anD, bf16* __restrict__ hOut,
    float* __restrict__ asOut, float* __restrict__ adOut,
    float* __restrict__ yout, int N) {
    constexpr int HC = H * C;
    constexpr int HCN = FINAL ? 1 : HN * CN;  // next-layer width
    constexpr int LPR = HC / 8;               // lanes per h-row (bf16x8 each)
    constexpr int EPI = 64 / LPR;             // edges in flight per iteration
    __shared__ int src_s[4 * 64];
    __shared__ float w_s[4 * 64 * H];
    __shared__ float xsr[FINAL ? 1 : 4 * HC];   // per-wave activated output row
    __shared__ float hsr[FINAL ? 1 : 4 * HCN];  // per-wave next-layer h row
    const int wvi = threadIdx.x >> 6;
    const int lane = threadIdx.x & 63;
    const int d = blockIdx.x * 4 + wvi;
    if (d >= N) return;  // no block-wide barriers below
    const int grp = lane / LPR;
    const int lin = lane - grp * LPR;
    const int ch0 = 8 * lin;
    const int h0 = ch0 / C;
    const int row = csr_off[d], end = csr_off[d + 1];

    float ad_d[H], c[H], den_p[H];
#pragma unroll
    for (int h = 0; h < H; ++h) {
        ad_d[h] = adb[d * H + h];
        c[h] = lrelu(asb[d * H + h] + ad_d[h]);  // shift constant = self-loop score
        den_p[h] = 0.f;
    }
    float acc[8];
#pragma unroll
    for (int r = 0; r < 8; ++r) acc[r] = 0.f;
    if (grp == 0) {  // self-loop contribution (weight 1 pre-normalization)
        uint4 pv = *(const uint4*)(hbuf + (size_t)d * HC + ch0);
        float2 p0 = bf2x(pv.x), p1 = bf2x(pv.y), p2 = bf2x(pv.z), p3 = bf2x(pv.w);
        acc[0] = p0.x; acc[1] = p0.y; acc[2] = p1.x; acc[3] = p1.y;
        acc[4] = p2.x; acc[5] = p2.y; acc[6] = p3.x; acc[7] = p3.y;
    }

    for (int base = row; base < end; base += 64) {
        int e = base + lane;
        int s = (e < end) ? (int)elsrc[e] : -1;
        if constexpr (H == 4) {
            float4 w4 = {0.f, 0.f, 0.f, 0.f};
            if (s >= 0) {
                float4 av = *(const float4*)(asb + s * 4);
                w4.x = __expf(lrelu(av.x + ad_d[0]) - c[0]);
                w4.y = __expf(lrelu(av.y + ad_d[1]) - c[1]);
                w4.z = __expf(lrelu(av.z + ad_d[2]) - c[2]);
                w4.w = __expf(lrelu(av.w + ad_d[3]) - c[3]);
                den_p[0] += w4.x;
                den_p[1] += w4.y;
                den_p[2] += w4.z;
                den_p[3] += w4.w;
            }
            *(float4*)&w_s[(wvi * 64 + lane) * 4] = w4;
        } else {
            float w0 = 0.f;
            if (s >= 0) {
                w0 = __expf(lrelu(asb[s] + ad_d[0]) - c[0]);
                den_p[0] += w0;
            }
            w_s[wvi * 64 + lane] = w0;
        }
        src_s[wvi * 64 + lane] = (s >= 0) ? s : 0;
        int nv = min(64, end - base);
#pragma unroll 4
        for (int k0 = 0; k0 < nv; k0 += EPI) {
            int k = k0 + grp;
            if (k < nv) {
                int sk = src_s[wvi * 64 + k];
                float w = w_s[(wvi * 64 + k) * H + h0];
                uint4 pv = *(const uint4*)(hbuf + (size_t)sk * HC + ch0);
                float2 p0 = bf2x(pv.x), p1 = bf2x(pv.y), p2 = bf2x(pv.z), p3 = bf2x(pv.w);
                acc[0] += w * p0.x; acc[1] += w * p0.y;
                acc[2] += w * p1.x; acc[3] += w * p1.y;
                acc[4] += w * p2.x; acc[5] += w * p2.y;
                acc[6] += w * p3.x; acc[7] += w * p3.y;
            }
        }
    }
#pragma unroll
    for (int h = 0; h < H; ++h) {
        float v = den_p[h];
#pragma unroll
        for (int o = 32; o > 0; o >>= 1) v += __shfl_xor(v, o, 64);
        den_p[h] = v + 1.0f;  // + self term
    }
#pragma unroll
    for (int o = LPR; o < 64; o <<= 1) {
#pragma unroll
        for (int r = 0; r < 8; ++r) acc[r] += __shfl_xor(acc[r], o, 64);
    }
    // epilogue: bias + activation; grp==0 lanes hold the full output row
    if (grp == 0) {
        float inv = 1.f / (den_p[h0] + 1e-16f);
        if constexpr (FINAL) {
            float4 o0, o1;
            float v0 = acc[0] * inv + bias[ch0 + 0];
            float v1 = acc[1] * inv + bias[ch0 + 1];
            float v2 = acc[2] * inv + bias[ch0 + 2];
            float v3 = acc[3] * inv + bias[ch0 + 3];
            float v4 = acc[4] * inv + bias[ch0 + 4];
            float v5 = acc[5] * inv + bias[ch0 + 5];
            float v6 = acc[6] * inv + bias[ch0 + 6];
            float v7 = acc[7] * inv + bias[ch0 + 7];
            o0.x = 1.f / (1.f + __expf(-v0));
            o0.y = 1.f / (1.f + __expf(-v1));
            o0.z = 1.f / (1.f + __expf(-v2));
            o0.w = 1.f / (1.f + __expf(-v3));
            o1.x = 1.f / (1.f + __expf(-v4));
            o1.y = 1.f / (1.f + __expf(-v5));
            o1.z = 1.f / (1.f + __expf(-v6));
            o1.w = 1.f / (1.f + __expf(-v7));
            *(float4*)(yout + (size_t)d * HC + ch0) = o0;
            *(float4*)(yout + (size_t)d * HC + ch0 + 4) = o1;
        } else {
#pragma unroll
            for (int r = 0; r < 8; ++r) {
                float v = acc[r] * inv + bias[ch0 + r];
                xsr[wvi * HC + ch0 + r] = v > 0.f ? v : 0.f;  // relu'd next-layer x
            }
        }
    }
    if constexpr (!FINAL) {
        __builtin_amdgcn_wave_barrier();  // xsr writes (same wave) before reads
        // next-layer transform: h = x @ Wn (Wn <=16KB, L1-resident)
        constexpr int OPL = (HCN + 63) / 64;  // outputs per lane
#pragma unroll
        for (int r = 0; r < OPL; ++r) {
            int j = lane + 64 * r;
            if (j < HCN) {
                float a = 0.f;
#pragma unroll 8
                for (int f = 0; f < HC; ++f) a += xsr[wvi * HC + f] * Wn[f * HCN + j];
                hOut[(size_t)d * HCN + j] = __float2bfloat16(a);
                hsr[wvi * HCN + j] = a;
            }
        }
        __builtin_amdgcn_wave_barrier();
        if (lane < HN) {  // alpha_s / alpha_d for next layer
            float s = 0.f, dv = 0.f;
#pragma unroll 8
            for (int cc = 0; cc < CN; ++cc) {
                float hv = hsr[wvi * HCN + lane * CN + cc];
                s += hv * anS[lane * CN + cc];
                dv += hv * anD[lane * CN + cc];
            }
            asOut[d * HN + lane] = s;
            adOut[d * HN + lane] = dv;
        }
    }
}

// ---------------- layer driver, templated on edge-index storage type
template <typename EIDX>
static void run_layers(const int* csr_off, const EIDX* elsrc, bf16* hA, bf16* hB,
                       float* asA, float* adA, float* asB, float* adB, float* y,
                       void* const* d_in, int N, hipStream_t stream) {
    const float* b1 = (const float*)d_in[8];
    const float* W2 = (const float*)d_in[9];
    const float* a2s = (const float*)d_in[10];
    const float* a2d = (const float*)d_in[11];
    const float* b2 = (const float*)d_in[12];
    const float* W3 = (const float*)d_in[13];
    const float* a3s = (const float*)d_in[14];
    const float* a3d = (const float*)d_in[15];
    const float* b3 = (const float*)d_in[16];
    const float* W4 = (const float*)d_in[17];
    const float* a4s = (const float*)d_in[18];
    const float* a4d = (const float*)d_in[19];
    const float* b4 = (const float*)d_in[20];
    const int g = cdiv(N, 4);
    // gat1 (4x32) + transform2 (->1x32)
    gat_fused<4, 32, 1, 32, false, EIDX><<<g, 256, 0, stream>>>(
        csr_off, elsrc, hA, asA, adA, b1, W2, a2s, a2d, hB, asB, adB, y, N);
    // gat2 (1x32) + transform3 (->4x32)
    gat_fused<1, 32, 4, 32, false, EIDX><<<g, 256, 0, stream>>>(
        csr_off, elsrc, hB, asB, adB, b2, W3, a3s, a3d, hA, asA, adA, y, N);
    // gat3 (4x32) + transform4 (->1x16)
    gat_fused<4, 32, 1, 16, false, EIDX><<<g, 256, 0, stream>>>(
        csr_off, elsrc, hA, asA, adA, b3, W4, a4s, a4d, hB, asB, adB, y, N);
    // gat4 (1x16) -> sigmoid f32 y
    gat_fused<1, 16, 1, 1, true, EIDX><<<g, 256, 0, stream>>>(
        csr_off, elsrc, hB, asB, adB, b4, W4, a4s, a4d, hA, asA, adA, y, N);
}

extern "C" void kernel_launch(void* const* d_in, const int* in_sizes, int n_in,
                              void* d_out, int out_size, void* d_ws, size_t ws_size,
                              hipStream_t stream) {
    const int N = in_sizes[0];
    const int E = in_sizes[2] / 2;
    const int* node_ids = (const int*)d_in[0];
    const float* feats = (const float*)d_in[1];
    const int* srcI = (const int*)d_in[2];
    const int* dstI = srcI + E;
    const float* emb = (const float*)d_in[4];
    const float* W1 = (const float*)d_in[5];
    const float* a1s = (const float*)d_in[6];
    const float* a1d = (const float*)d_in[7];
    float* y = (float*)d_out;

    const int nb = cdiv(N, 256);

    // workspace layout (~29 MB @ N=50000, E=800000)
    float* asA = (float*)d_ws;                       // N*4 f32
    float* adA = asA + (size_t)N * 4;                // N*4 f32
    float* asB = adA + (size_t)N * 4;                // N*4 f32
    float* adB = asB + (size_t)N * 4;                // N*4 f32
    bf16* hA = (bf16*)(adB + (size_t)N * 4);         // N*128 bf16
    bf16* hB = hA + (size_t)N * 128;                 // N*128 bf16
    int* counts = (int*)(hB + (size_t)N * 128);      // N
    int* csr_off = counts + N;                       // N+1
    int* cursor = csr_off + N + 1;                   // N
    int* elsrc = cursor + N;                         // E ints (or E ushorts)
    int* bsum = elsrc + E;                           // nb (<=1024)

    size_t need = (size_t)N * 4 * 4 * 4 + (size_t)N * 128 * 2 * 2 +
                  ((size_t)3 * N + 1 + E + 1024) * 4;
    if (ws_size < need || nb > 1024) {
        fill_sentinel<<<cdiv(out_size, 256), 256, 0, stream>>>(y, out_size);
        return;
    }

    hipMemsetAsync(counts, 0, (size_t)N * 4, stream);
    // fused: edge counting || layer-1 transform (independent work, one dispatch)
    count_and_t1<<<CB + cdiv(N, 2), 256, 0, stream>>>(dstI, counts, E, node_ids, feats,
                                                      emb, W1, a1s, a1d, hA, asA, adA, N);
    scan_blocksums<<<nb, 256, 0, stream>>>(counts, bsum, N);
    scan_bsums<<<1, 1024, 0, stream>>>(bsum, nb);
    scan_final<<<nb, 256, 0, stream>>>(counts, bsum, csr_off, cursor, N);

    if (N <= 65536) {
        ushort* el16 = (ushort*)elsrc;
        csr_fill_u16<<<cdiv(E, 256), 256, 0, stream>>>(srcI, dstI, cursor, el16, E);
        run_layers<ushort>(csr_off, el16, hA, hB, asA, adA, asB, adB, y, d_in, N, stream);
    } else {
        csr_fill_i32<<<cdiv(E, 256), 256, 0, stream>>>(srcI, dstI, cursor, elsrc, E);
        run_layers<int>(csr_off, elsrc, hA, hB, asA, adA, asB, adB, y, d_in, N, stream);
    }
}